// Round 3
// baseline (24.645 us; speedup 1.0000x reference)
//
#include <hip/hip_runtime.h>
#include <math.h>

#define DQ    512        // input feature dim
#define NQ    4          // qubits
#define LQ    2          // layers
#define RPB   32         // rows per block
#define BLOCK 256

// Sum across a 16-lane DPP row (pure VALU).
__device__ __forceinline__ float rowsum16(float v) {
    int x;
    x = __builtin_amdgcn_update_dpp(0, __float_as_int(v), 0x121, 0xF, 0xF, true); // ror:1
    v += __int_as_float(x);
    x = __builtin_amdgcn_update_dpp(0, __float_as_int(v), 0x122, 0xF, 0xF, true); // ror:2
    v += __int_as_float(x);
    x = __builtin_amdgcn_update_dpp(0, __float_as_int(v), 0x124, 0xF, 0xF, true); // ror:4
    v += __int_as_float(x);
    x = __builtin_amdgcn_update_dpp(0, __float_as_int(v), 0x128, 0xF, 0xF, true); // ror:8
    v += __int_as_float(x);
    return v;
}

// Sum across a 32-lane group: 16-lane DPP sum + xor-16 swizzle (within 32-lane groups).
__device__ __forceinline__ float sum32(float v) {
    v = rowsum16(v);
    const int x = __builtin_amdgcn_ds_swizzle(__float_as_int(v), 0x401F); // xor 16, and 0x1F
    return v + __int_as_float(x);
}

__device__ __forceinline__ float fast_tanh(float x) {
    const float e = __expf(2.0f * x);
    return 1.0f - 2.0f / (e + 1.0f);   // robust: e=inf -> 1, e=0 -> -1
}

__global__ __launch_bounds__(BLOCK, 4) void qrnn_kernel(
    const float* __restrict__ inputs,   // (B,512)
    const float* __restrict__ prev_h,   // (B,4)
    const float* __restrict__ W_enc,    // (516,4)
    const float* __restrict__ b_enc,    // (4)
    const float* __restrict__ theta,    // (2,4,3)
    const float* __restrict__ W_out,    // (4,4)
    const float* __restrict__ b_out,    // (4)
    float* __restrict__ out,            // (B,4)
    int B)
{
    __shared__ float4 sC4[RPB];            // cos(half-angle) per row
    __shared__ float4 sS4[RPB];            // sin(half-angle) per row
    __shared__ float  sU[LQ * NQ * 8];     // 8 unitaries, 2x2 complex each

    const int tid  = threadIdx.x;
    const int lane = tid & 63;
    const int wave = tid >> 6;
    const int g    = lane >> 5;            // which 32-lane half owns which row
    const int j    = lane & 31;
    const int blockBase = blockIdx.x * RPB;
    const int rbase = wave * 8;            // 8 rows per wave: 4 passes x 2 rows

    // ---------------- Phase 0: shared unitaries U = RY * RZ * RX ----------------
    if (tid < LQ * NQ) {
        const int l = tid >> 2, q = tid & 3;
        const float a  = theta[(l * NQ + q) * 3 + 0] * 0.5f;
        const float b  = theta[(l * NQ + q) * 3 + 1] * 0.5f;
        const float cc = theta[(l * NQ + q) * 3 + 2] * 0.5f;
        float sa, ca, sb, cb, sy, cy;
        sincosf(a,  &sa, &ca);
        sincosf(b,  &sb, &cb);
        sincosf(cc, &sy, &cy);
        const float m00r =  ca * cb, m00i = -ca * sb;
        const float m01r = -sa * sb, m01i = -sa * cb;
        const float m10r =  sa * sb, m10i = -sa * cb;
        const float m11r =  ca * cb, m11i =  ca * sb;
        float* u = &sU[tid * 8];
        u[0] = cy * m00r - sy * m10r;  u[1] = cy * m00i - sy * m10i;  // U00
        u[2] = cy * m01r - sy * m11r;  u[3] = cy * m01i - sy * m11i;  // U01
        u[4] = sy * m00r + cy * m10r;  u[5] = sy * m00i + cy * m10i;  // U10
        u[6] = sy * m01r + cy * m11r;  u[7] = sy * m01i + cy * m11i;  // U11
    }

    // ---------------- Phase 1: encoding matmul, one row per 32-lane group -------
    // Lane j owns float4 chunks f = j + 32c (c=0..3) of its row -> features 4f..4f+3.
    const float4* __restrict__ W4  = (const float4*)W_enc;
    const float4* __restrict__ in4 = (const float4*)inputs;

    float4 wreg[4][4];                      // W rows for this lane's 16 features
#pragma unroll
    for (int c = 0; c < 4; ++c)
#pragma unroll
        for (int k = 0; k < 4; ++k)
            wreg[c][k] = W4[4 * j + 128 * c + k];

    // 8-step software pipeline over 16 load-steps (4 passes x 4 chunks)
    float4 buf[8];
#pragma unroll
    for (int s = 0; s < 8; ++s) {
        const int p = s >> 2, c = s & 3;
        buf[s] = in4[(size_t)(blockBase + rbase + 2 * p + g) * (DQ / 4) + j + 32 * c];
    }

    float4 acc = make_float4(0.f, 0.f, 0.f, 0.f);
#pragma unroll
    for (int s = 0; s < 16; ++s) {
        const int p = s >> 2, c = s & 3;
        const float4 x = buf[s & 7];
        if (s + 8 < 16) {
            const int p2 = (s + 8) >> 2, c2 = (s + 8) & 3;
            buf[s & 7] = in4[(size_t)(blockBase + rbase + 2 * p2 + g) * (DQ / 4) + j + 32 * c2];
        }
        if (c == 0) acc = make_float4(0.f, 0.f, 0.f, 0.f);
        acc.x += x.x * wreg[c][0].x + x.y * wreg[c][1].x + x.z * wreg[c][2].x + x.w * wreg[c][3].x;
        acc.y += x.x * wreg[c][0].y + x.y * wreg[c][1].y + x.z * wreg[c][2].y + x.w * wreg[c][3].y;
        acc.z += x.x * wreg[c][0].z + x.y * wreg[c][1].z + x.z * wreg[c][2].z + x.w * wreg[c][3].z;
        acc.w += x.x * wreg[c][0].w + x.y * wreg[c][1].w + x.z * wreg[c][2].w + x.w * wreg[c][3].w;
        if (c == 3) {
            // full row dot product within the 32-lane group
            float s0 = sum32(acc.x);
            float s1 = sum32(acc.y);
            float s2 = sum32(acc.z);
            float s3 = sum32(acc.w);
            if (j == 0) {
                const int rl = rbase + 2 * p + g;
                const float4 ph = *(const float4*)(prev_h + (size_t)(blockBase + rl) * 4);
                const float4 wt0 = W4[512], wt1 = W4[513], wt2 = W4[514], wt3 = W4[515];
                const float4 bE  = *(const float4*)b_enc;
                s0 += ph.x * wt0.x + ph.y * wt1.x + ph.z * wt2.x + ph.w * wt3.x + bE.x;
                s1 += ph.x * wt0.y + ph.y * wt1.y + ph.z * wt2.y + ph.w * wt3.y + bE.y;
                s2 += ph.x * wt0.z + ph.y * wt1.z + ph.z * wt2.z + ph.w * wt3.z + bE.z;
                s3 += ph.x * wt0.w + ph.y * wt1.w + ph.z * wt2.w + ph.w * wt3.w + bE.w;
                const float kHalfPi = 1.57079632679489662f;
                const float h0 = fast_tanh(s0) * kHalfPi;
                const float h1 = fast_tanh(s1) * kHalfPi;
                const float h2 = fast_tanh(s2) * kHalfPi;
                const float h3 = fast_tanh(s3) * kHalfPi;
                float sn0, cs0, sn1, cs1, sn2, cs2, sn3, cs3;
                __sincosf(h0, &sn0, &cs0);
                __sincosf(h1, &sn1, &cs1);
                __sincosf(h2, &sn2, &cs2);
                __sincosf(h3, &sn3, &cs3);
                sC4[rl] = make_float4(cs0, cs1, cs2, cs3);
                sS4[rl] = make_float4(sn0, sn1, sn2, sn3);
            }
        }
    }

    __syncthreads();

    // ---------------- Phase 2: per-row 16-amplitude circuit (one thread per row) --
    if (tid < RPB) {
        const int row = blockBase + tid;
        const float4 c4 = sC4[tid];
        const float4 s4 = sS4[tid];
        const float cq[4] = { c4.x, c4.y, c4.z, c4.w };
        const float sq[4] = { s4.x, s4.y, s4.z, s4.w };

        float ar[16], ai[16];
#pragma unroll
        for (int jj = 0; jj < 16; ++jj) {
            float v = ((jj >> 3) & 1) ? sq[0] : cq[0];
            v      *= ((jj >> 2) & 1) ? sq[1] : cq[1];
            v      *= ((jj >> 1) & 1) ? sq[2] : cq[2];
            v      *= ((jj >> 0) & 1) ? sq[3] : cq[3];
            ar[jj] = v;
            ai[jj] = 0.f;
        }

#pragma unroll
        for (int l = 0; l < LQ; ++l) {
#pragma unroll
            for (int q = 0; q < NQ; ++q) {
                const float* u = &sU[(l * NQ + q) * 8];
                const float u00r = u[0], u00i = u[1], u01r = u[2], u01i = u[3];
                const float u10r = u[4], u10i = u[5], u11r = u[6], u11i = u[7];
                const int bit = 1 << (3 - q);
#pragma unroll
                for (int jj = 0; jj < 16; ++jj) {
                    if (jj & bit) continue;          // compile-time resolved
                    const int kk = jj | bit;
                    const float a0r = ar[jj], a0i = ai[jj];
                    const float a1r = ar[kk], a1i = ai[kk];
                    ar[jj] = u00r * a0r - u00i * a0i + u01r * a1r - u01i * a1i;
                    ai[jj] = u00r * a0i + u00i * a0r + u01r * a1i + u01i * a1r;
                    ar[kk] = u10r * a0r - u10i * a0i + u11r * a1r - u11i * a1i;
                    ai[kk] = u10r * a0i + u10i * a0r + u11r * a1i + u11i * a1r;
                }
            }
#pragma unroll
            for (int q = 0; q < NQ - 1; ++q) {       // CNOT chain
                const int cb = 1 << (3 - q), tb = 1 << (2 - q);
#pragma unroll
                for (int jj = 0; jj < 16; ++jj) {
                    if ((jj & cb) && !(jj & tb)) {   // compile-time resolved
                        const int kk = jj | tb;
                        float t;
                        t = ar[jj]; ar[jj] = ar[kk]; ar[kk] = t;
                        t = ai[jj]; ai[jj] = ai[kk]; ai[kk] = t;
                    }
                }
            }
        }

        // PauliZ expectations
        float ev[4] = { 0.f, 0.f, 0.f, 0.f };
#pragma unroll
        for (int jj = 0; jj < 16; ++jj) {
            const float p = ar[jj] * ar[jj] + ai[jj] * ai[jj];
#pragma unroll
            for (int q = 0; q < 4; ++q)
                ev[q] += (jj & (1 << (3 - q))) ? -p : p;
        }

        // output layer
        float ob[4];
#pragma unroll
        for (int jj = 0; jj < 4; ++jj) {
            float t = b_out[jj];
#pragma unroll
            for (int q = 0; q < 4; ++q) t += ev[q] * W_out[q * 4 + jj];
            ob[jj] = fast_tanh(t);
        }
        *(float4*)(out + (size_t)row * 4) = make_float4(ob[0], ob[1], ob[2], ob[3]);
    }
}

extern "C" void kernel_launch(void* const* d_in, const int* in_sizes, int n_in,
                              void* d_out, int out_size, void* d_ws, size_t ws_size,
                              hipStream_t stream) {
    const float* inputs = (const float*)d_in[0];
    const float* prev_h = (const float*)d_in[1];
    const float* W_enc  = (const float*)d_in[2];
    const float* b_enc  = (const float*)d_in[3];
    const float* theta  = (const float*)d_in[4];
    const float* W_out  = (const float*)d_in[5];
    const float* b_out  = (const float*)d_in[6];
    float* out = (float*)d_out;

    const int B = in_sizes[0] / DQ;                 // 32768
    const int grid = (B + RPB - 1) / RPB;           // 1024

    qrnn_kernel<<<grid, BLOCK, 0, stream>>>(inputs, prev_h, W_enc, b_enc, theta,
                                            W_out, b_out, out, B);
}